// Round 9
// baseline (3472.874 us; speedup 1.0000x reference)
//
#include <hip/hip_runtime.h>
#include <hip/hip_bf16.h>

#define BB 256   // batch
#define TT 512   // time
#define HH 256   // hidden
#define EE 128   // embed
#define KK 15    // tags
#define GB 16    // batch rows per block

typedef __attribute__((ext_vector_type(8))) short short8;
typedef __attribute__((ext_vector_type(4))) float floatx4;

__device__ __forceinline__ float fsig(float x) { return 1.0f / (1.0f + __expf(-x)); }
__device__ __forceinline__ float ftanh(float x) {
    float e = __expf(2.0f * x);
    return 1.0f - 2.0f / (e + 1.0f);
}
__device__ __forceinline__ unsigned short f2b(float f) {
    __hip_bfloat16 h = __float2bfloat16(f);
    return *reinterpret_cast<unsigned short*>(&h);
}

// ---------------- fused prep: transpose + gate tables + fragment-linear weights ----------------
// blocks 0..1023: transpose cids/labels. 1024..2047: tables (bias + x@Wih folded).
// 2048..2307: wbf (Whh bf16, A-fragment-linear) + fcwb (fcW bf16, A-fragment-linear).
__global__ void prep_fused(const int* __restrict__ cids, const int* __restrict__ labels,
                           int* __restrict__ cidsT, int* __restrict__ labelsT,
                           const float* __restrict__ embed,
                           const float* __restrict__ WihF, const float* __restrict__ bF,
                           const float* __restrict__ WihB, const float* __restrict__ bB,
                           const float* __restrict__ WhhF, const float* __restrict__ WhhB,
                           const float* __restrict__ fcW,
                           float* __restrict__ tableF, float* __restrict__ tableB,
                           unsigned short* __restrict__ wbf, unsigned short* __restrict__ fcwb) {
    const int bidx = blockIdx.x;
    const int tid = threadIdx.x;
    if (bidx < 1024) {
        int idx = bidx * 256 + tid;
        int which = idx >> 17;
        int r = idx & 131071;
        int b = r >> 9, t = r & 511;
        if (which == 0) cidsT[t * BB + b] = cids[b * TT + t];
        else            labelsT[t * BB + b] = labels[b * TT + t];
    } else if (bidx < 2048) {
        int idx = (bidx - 1024) * 256 + tid;
        int d = idx >> 17;
        int r = idx & 131071;
        int v = r >> 10, j = r & 1023;
        const float* Wih = d ? WihB : WihF;
        const float* bias = d ? bB : bF;
        float s = bias[j];
        const float* em = embed + v * EE;
        const float* wr = Wih + j * EE;
#pragma unroll 8
        for (int e = 0; e < EE; ++e) s += em[e] * wr[e];
        (d ? tableB : tableF)[v * 1024 + j] = s;
    } else {
        int unit = (bidx - 2048) * 256 + tid;   // 0..66559
        if (unit < 65536) {
            // wbf: [dir][m(64)][kb(8)][lane(64)][8]; A[row=lane&15][k=kb*32+(lane>>4)*8+j]
            int d = unit >> 15;
            int r15 = unit & 32767;
            int m = r15 >> 9;
            int kb = (r15 >> 6) & 7;
            int ln = r15 & 63;
            int row = (m >> 4) * 256 + (m & 15) * 16 + (ln & 15);
            int kst = kb * 32 + (ln >> 4) * 8;
            const float* src = (d ? WhhB : WhhF) + (size_t)row * HH + kst;
            short8 f;
#pragma unroll
            for (int j = 0; j < 8; ++j) f[j] = (short)f2b(src[j]);
            *(short8*)&wbf[(size_t)unit * 8] = f;
        } else {
            // fcwb: [dir][kb(8)][lane(64)][8]; A[row=tag][k]
            int u2 = unit - 65536;               // 0..1023
            int d = u2 >> 9;
            int r9 = u2 & 511;
            int kb = r9 >> 6;
            int ln = r9 & 63;
            int tag = ln & 15;
            int kst = kb * 32 + (ln >> 4) * 8;
            short8 f;
#pragma unroll
            for (int j = 0; j < 8; ++j)
                f[j] = (tag < KK) ? (short)f2b(fcW[tag * (2 * HH) + d * HH + kst + j]) : (short)0;
            *(short8*)&fcwb[(size_t)u2 * 8] = f;
        }
    }
}

// ---------------- BiLSTM: batch-partitioned, weights streamed from XCD L2 ----------------
// 32 blocks x 1024 threads (16 waves). Block: dir=bid>>4, g=bid&15 -> batch rows [g*16,g*16+16).
// Wave w owns h-cols [w*16, w*16+16) for all 4 gates: M-tiles {q*16+w}. A=W (streamed
// fragment-linear from L2, double-buffered), B=h (LDS ring, B-fragment-linear). Nonlinearity
// lane-local (batch=lane&15, cols hi*4+r). em: waves 0..7 one K-chunk partial each ->
// LDS, wave 15 reduces with lag 2. One raw s_barrier/step; no cross-block communication.
__global__ void __launch_bounds__(1024)
bilstm(const float* __restrict__ tableF, const float* __restrict__ tableB,
       const unsigned short* __restrict__ wbf, const unsigned short* __restrict__ fcwb,
       const int* __restrict__ cidsT,
       float* __restrict__ emF, float* __restrict__ emB) {
    const int bid = blockIdx.x;
    const int dir = bid >> 4;
    const int g   = bid & 15;
    const int tid = threadIdx.x;
    const int w    = tid >> 6;       // 0..15
    const int lane = tid & 63;
    const int lo   = lane & 15;
    const int hi   = lane >> 4;      // 0..3

    const float* table = dir ? tableB : tableF;
    float* emOut       = dir ? emB : emF;

    __shared__ __align__(16) unsigned short hfr[2][4096];   // 16 KiB: [buf][kb(8)][l(64)][8]
    __shared__ __align__(16) float emtmp[2][8][64][4];      // 16 KiB

    // weight stream base: fragment (q,kb) at wbase + q*65536 + kb*512 (shorts)
    const unsigned short* wbase = wbf + (size_t)(dir * 64 + w) * 4096 + lane * 8;

    short8 fcA = {};
    if (w < 8) fcA = *(const short8*)(fcwb + (size_t)(dir * 8 + w) * 512 + lane * 8);

    const int bb0 = g * GB;
    // h write index (B-fragment-linear): col c = w*16 + hi*4 + r, batch = lo
    const int hwidx = (w >> 1) * 512 + (((w & 1) * 2 + (hi >> 1)) * 16 + lo) * 8 + (hi & 1) * 4;

    // cid pipeline (2 ahead) + table prefetch for s=0
    int t0 = dir ? (TT - 1) : 0;
    int cid_cur = cidsT[t0 * BB + bb0 + lo];
    int t1 = dir ? (TT - 2) : 1;
    int cid_next = cidsT[t1 * BB + bb0 + lo];
    floatx4 tpre[4];
#pragma unroll
    for (int q = 0; q < 4; ++q)
        tpre[q] = *(const floatx4*)(table + (size_t)cid_cur * 1024 + q * HH + w * 16 + hi * 4);

    float cst[4] = {0.f, 0.f, 0.f, 0.f};

    for (int s = 0; s <= TT + 1; ++s) {
        // ---- gates for step s ----
        if (s < TT) {
            floatx4 acc[4];
#pragma unroll
            for (int q = 0; q < 4; ++q) acc[q] = tpre[q];

            int cid_nn = 0;
            if (s + 2 < TT) {
                int t2 = dir ? (TT - 1 - (s + 2)) : (s + 2);
                cid_nn = cidsT[t2 * BB + bb0 + lo];
            }

            if (s > 0) {
                const unsigned short* hb = hfr[(s + 1) & 1];   // h_{s-1}
                short8 wAa[4], wAb[4];
#pragma unroll
                for (int q = 0; q < 4; ++q)
                    wAa[q] = *(const short8*)(wbase + q * 65536);
#pragma unroll
                for (int kp = 0; kp < 4; ++kp) {
                    // even kb = 2*kp: compute with wAa, prefetch wAb (kb+1)
#pragma unroll
                    for (int q = 0; q < 4; ++q)
                        wAb[q] = *(const short8*)(wbase + q * 65536 + (2 * kp + 1) * 512);
                    {
                        short8 hk = *(const short8*)&hb[(2 * kp) * 512 + lane * 8];
#pragma unroll
                        for (int q = 0; q < 4; ++q)
                            acc[q] = __builtin_amdgcn_mfma_f32_16x16x32_bf16(wAa[q], hk, acc[q], 0, 0, 0);
                    }
                    // odd kb = 2*kp+1: compute with wAb, prefetch wAa (kb+1)
                    if (kp < 3) {
#pragma unroll
                        for (int q = 0; q < 4; ++q)
                            wAa[q] = *(const short8*)(wbase + q * 65536 + (2 * kp + 2) * 512);
                    }
                    {
                        short8 hk = *(const short8*)&hb[(2 * kp + 1) * 512 + lane * 8];
#pragma unroll
                        for (int q = 0; q < 4; ++q)
                            acc[q] = __builtin_amdgcn_mfma_f32_16x16x32_bf16(wAb[q], hk, acc[q], 0, 0, 0);
                    }
                }
            }

            // table prefetch for s+1 (overlaps nonlinearity)
            if (s + 1 < TT) {
#pragma unroll
                for (int q = 0; q < 4; ++q)
                    tpre[q] = *(const floatx4*)(table + (size_t)cid_next * 1024 + q * HH + w * 16 + hi * 4);
            }
            cid_next = cid_nn;

            // nonlinearity (lane-local) + h write into B-fragment-linear LDS ring
            unsigned hbv[4];
#pragma unroll
            for (int r = 0; r < 4; ++r) {
                float iv = acc[0][r], fv = acc[1][r], gv = acc[2][r], ov = acc[3][r];
                float cn = fsig(fv) * cst[r] + fsig(iv) * ftanh(gv);
                cst[r] = cn;
                hbv[r] = (unsigned)f2b(fsig(ov) * ftanh(cn));
            }
            uint2 pv;
            pv.x = hbv[0] | (hbv[1] << 16);
            pv.y = hbv[2] | (hbv[3] << 16);
            *(uint2*)&hfr[s & 1][hwidx] = pv;
        }

        // ---- em partial for h_{s-1}: waves 0..7, one K-chunk each ----
        if (w < 8 && s >= 1 && s <= TT) {
            const unsigned short* hb = hfr[(s + 1) & 1];
            short8 hk = *(const short8*)&hb[w * 512 + lane * 8];
            floatx4 ez = {0.f, 0.f, 0.f, 0.f};
            ez = __builtin_amdgcn_mfma_f32_16x16x32_bf16(fcA, hk, ez, 0, 0, 0);
            *(floatx4*)&emtmp[(s + 1) & 1][w][lane][0] = ez;
        }

        // ---- reduce em(h_{s-2}) on wave 15 ----
        if (w == 15 && s >= 2) {
            const int hidx = s - 2;
            floatx4 sum = *(const floatx4*)&emtmp[s & 1][0][lane][0];
#pragma unroll
            for (int wv = 1; wv < 8; ++wv)
                sum += *(const floatx4*)&emtmp[s & 1][wv][lane][0];
            const int te = dir ? (TT - 1 - hidx) : hidx;
            float* eo = emOut + ((size_t)te * BB + bb0 + lo) * KK;
#pragma unroll
            for (int r = 0; r < 4; ++r) {
                int tag = hi * 4 + r;
                if (tag < KK) eo[tag] = sum[r];
            }
        }

        // ---- one barrier per step: LDS drained only (loads span steps) ----
        asm volatile("s_waitcnt lgkmcnt(0)" ::: "memory");
        __builtin_amdgcn_sched_barrier(0);
        __builtin_amdgcn_s_barrier();
    }
}

// ---------------- CRF partition (den): 16-lane group per batch row, em prefetch ----------------
__global__ void crf_den(const float* __restrict__ emF, const float* __restrict__ emB,
                        const float* __restrict__ fcb, const float* __restrict__ start_t,
                        const float* __restrict__ end_t, const float* __restrict__ trans,
                        float* __restrict__ den) {
    const int tid = threadIdx.x;
    const int j = tid & 15;
    const int grp = tid >> 4;               // 0..7
    const int b = blockIdx.x * 8 + grp;
    const bool valid = j < KK;

    __shared__ float expT[15][16];
    for (int idx = tid; idx < 240; idx += 128) {
        int i = idx >> 4, jj = idx & 15;
        expT[i][jj] = (jj < KK) ? __expf(trans[i * KK + jj]) : 0.f;
    }
    __syncthreads();

    float fcbj = valid ? fcb[j] : 0.f;
    float alpha = -1e30f;
    if (valid) alpha = start_t[j] + emF[b * KK + j] + emB[b * KK + j] + fcbj;

    float emv_nxt = 0.f;
    if (valid) emv_nxt = emF[(1 * BB + b) * KK + j] + emB[(1 * BB + b) * KK + j];

    for (int t = 1; t < TT; ++t) {
        float emv = emv_nxt;
        if (valid && t + 1 < TT)
            emv_nxt = emF[((t + 1) * BB + b) * KK + j] + emB[((t + 1) * BB + b) * KK + j];
        float m = alpha;
#pragma unroll
        for (int off = 8; off; off >>= 1)
            m = fmaxf(m, __shfl_xor(m, off, 16));
        float e = __expf(alpha - m);
        float S = 0.f;
#pragma unroll
        for (int i = 0; i < KK; ++i)
            S += __shfl(e, i, 16) * expT[i][j];
        float na = m + __logf(S) + emv + fcbj;
        alpha = valid ? na : -1e30f;
    }
    float v = valid ? (alpha + end_t[j]) : -1e30f;
    float m = v;
#pragma unroll
    for (int off = 8; off; off >>= 1) m = fmaxf(m, __shfl_xor(m, off, 16));
    float e = __expf(v - m);
#pragma unroll
    for (int off = 8; off; off >>= 1) e += __shfl_xor(e, off, 16);
    if (j == 0) den[b] = m + __logf(e);
}

// ---------------- CRF numerator partials over t-chunks ----------------
__global__ void crf_num_part(const float* __restrict__ emF, const float* __restrict__ emB,
                             const float* __restrict__ fcb, const float* __restrict__ start_t,
                             const float* __restrict__ trans, const int* __restrict__ labelsT,
                             float* __restrict__ part) {
    const int b = threadIdx.x;
    const int q = blockIdx.x;
    const int t0 = q * 64;
    float p = 0.f;
    int lp = (t0 > 0) ? labelsT[(t0 - 1) * BB + b] : 0;
    for (int t = t0; t < t0 + 64; ++t) {
        int l = labelsT[t * BB + b];
        float em = emF[(t * BB + b) * KK + l] + emB[(t * BB + b) * KK + l] + fcb[l];
        if (t == 0) p += start_t[l] + em;
        else        p += trans[lp * KK + l] + em;
        lp = l;
    }
    part[q * BB + b] = p;
}

// ---------------- finalize ----------------
__global__ void finalize(const float* __restrict__ part, const float* __restrict__ den,
                         const float* __restrict__ end_t, const int* __restrict__ labelsT,
                         float* __restrict__ out) {
    const int b = threadIdx.x;
    float num = 0.f;
#pragma unroll
    for (int q = 0; q < 8; ++q) num += part[q * BB + b];
    num += end_t[labelsT[(TT - 1) * BB + b]];
    float v = num - den[b];
    __shared__ float red[256];
    red[b] = v;
    __syncthreads();
    for (int st = 128; st; st >>= 1) {
        if (b < st) red[b] += red[b + st];
        __syncthreads();
    }
    if (b == 0) out[0] = -(red[0] / (float)BB);
}

extern "C" void kernel_launch(void* const* d_in, const int* in_sizes, int n_in,
                              void* d_out, int out_size, void* d_ws, size_t ws_size,
                              hipStream_t stream) {
    const int* char_ids   = (const int*)d_in[0];
    const int* labels     = (const int*)d_in[1];
    const float* embed    = (const float*)d_in[3];
    const float* WihF     = (const float*)d_in[4];
    const float* WhhF     = (const float*)d_in[5];
    const float* bF       = (const float*)d_in[6];
    const float* WihB     = (const float*)d_in[7];
    const float* WhhB     = (const float*)d_in[8];
    const float* bB       = (const float*)d_in[9];
    const float* fcW      = (const float*)d_in[10];
    const float* fcb      = (const float*)d_in[11];
    const float* start_t  = (const float*)d_in[12];
    const float* end_t    = (const float*)d_in[13];
    const float* trans    = (const float*)d_in[14];

    char* w = (char*)d_ws;
    float* tableF = (float*)w;                 w += 128 * 1024 * 4;
    float* tableB = (float*)w;                 w += 128 * 1024 * 4;
    int* cidsT    = (int*)w;                   w += 512 * 256 * 4;
    int* labelsT  = (int*)w;                   w += 512 * 256 * 4;
    unsigned short* wbf  = (unsigned short*)w; w += 65536 * 8 * 2;    // 1 MiB
    unsigned short* fcwb = (unsigned short*)w; w += 1024 * 8 * 2;     // 16 KiB
    float* emF    = (float*)w;                 w += 512 * 256 * 15 * 4;
    float* emB    = (float*)w;                 w += 512 * 256 * 15 * 4;
    float* den    = (float*)w;                 w += 256 * 4;
    float* part   = (float*)w;                 w += 8 * 256 * 4;

    prep_fused<<<2308, 256, 0, stream>>>(char_ids, labels, cidsT, labelsT,
                                         embed, WihF, bF, WihB, bB, WhhF, WhhB, fcW,
                                         tableF, tableB, wbf, fcwb);

    bilstm<<<32, 1024, 0, stream>>>(tableF, tableB, wbf, fcwb, cidsT, emF, emB);

    crf_den<<<32, 128, 0, stream>>>(emF, emB, fcb, start_t, end_t, trans, den);
    crf_num_part<<<8, 256, 0, stream>>>(emF, emB, fcb, start_t, trans, labelsT, part);
    finalize<<<1, 256, 0, stream>>>(part, den, end_t, labelsT, (float*)d_out);
}

// Round 10
// 927.609 us; speedup vs baseline: 3.7439x; 3.7439x over previous
//
#include <hip/hip_runtime.h>
#include <hip/hip_bf16.h>

#define BB 256   // batch
#define TT 512   // time
#define HH 256   // hidden
#define EE 128   // embed
#define KK 15    // tags
#define GB 16    // batch rows per group
#define NCH 4    // time chunks
#define CL 128   // chunk length
#define WU 64    // warm-up steps

typedef __attribute__((ext_vector_type(8))) short short8;
typedef __attribute__((ext_vector_type(4))) float floatx4;
typedef __attribute__((ext_vector_type(4))) unsigned int uint4v;

__device__ __forceinline__ float fsig(float x) { return 1.0f / (1.0f + __expf(-x)); }
__device__ __forceinline__ float ftanh(float x) {
    float e = __expf(2.0f * x);
    return 1.0f - 2.0f / (e + 1.0f);
}
__device__ __forceinline__ unsigned short f2b(float f) {
    __hip_bfloat16 h = __float2bfloat16(f);
    return *reinterpret_cast<unsigned short*>(&h);
}

// ---------------- fused prep: transpose ids/labels + build gate tables ----------------
__global__ void prep_fused(const int* __restrict__ cids, const int* __restrict__ labels,
                           int* __restrict__ cidsT, int* __restrict__ labelsT,
                           const float* __restrict__ embed,
                           const float* __restrict__ WihF, const float* __restrict__ bF,
                           const float* __restrict__ WihB, const float* __restrict__ bB,
                           float* __restrict__ tableF, float* __restrict__ tableB) {
    const int bidx = blockIdx.x;
    const int tid = threadIdx.x;
    if (bidx < 1024) {
        int idx = bidx * 256 + tid;          // 0..262143
        int which = idx >> 17;
        int r = idx & 131071;
        int b = r >> 9, t = r & 511;
        if (which == 0) cidsT[t * BB + b] = cids[b * TT + t];
        else            labelsT[t * BB + b] = labels[b * TT + t];
    } else {
        int idx = (bidx - 1024) * 256 + tid; // 0..262143
        int d = idx >> 17;
        int r = idx & 131071;
        int v = r >> 10, j = r & 1023;
        const float* Wih = d ? WihB : WihF;
        const float* bias = d ? bB : bF;
        float s = bias[j];
        const float* em = embed + v * EE;
        const float* wr = Wih + j * EE;
#pragma unroll 8
        for (int e = 0; e < EE; ++e) s += em[e] * wr[e];
        (d ? tableB : tableF)[v * 1024 + j] = s;
    }
}

// ---------------- BiLSTM: time-chunked (warm-up), fan-in 2, tag-in-data exchange ----------------
// 256 blocks x 512 threads, cooperative, 1 block/CU. bid = jb*128 + gi2;
// gi2 = dir*64 + g*4 + c (dir, batch-group, time-chunk); jb in 0..1 owns h-cols [jb*128,+128).
// Chunk c covers real t in [c*128, c*128+128), warm-up WU steps from zero state (seed chunks
// c=0 fwd / c=3 bwd exact, no warm-up). Wave wv (0..7) owns cols jb*128+wv*16+(lane&15), 4 gates
// register-resident (128 VGPR). hws slab per (gi2): [parity][col(256)][b(16)] u32 tagged words.
// h_s -> parity s&1 tag s+1; consumer at step s polls parity (s+1)&1 for tag s (4-deep ring).
__global__ void __launch_bounds__(512, 2)
bilstm(const float* __restrict__ tableF, const float* __restrict__ tableB,
       const float* __restrict__ WhhF, const float* __restrict__ WhhB,
       const float* __restrict__ fcW,
       const int* __restrict__ cidsT,
       unsigned* __restrict__ hws,
       float* __restrict__ emF, float* __restrict__ emB) {
    const int bid = blockIdx.x;
    const int gi2 = bid & 127;
    const int jb  = bid >> 7;          // 0..1
    const int dir = gi2 >> 6;
    const int g   = (gi2 >> 2) & 15;
    const int c   = gi2 & 3;
    const int tid = threadIdx.x;
    const int lane = tid & 63;
    const int wv  = tid >> 6;          // 0..7
    const int lo  = lane & 15;
    const int hi  = lane >> 4;         // 0..3

    const int warm   = (dir == 0) ? (c == 0 ? 0 : WU) : (c == NCH - 1 ? 0 : WU);
    const int S      = warm + CL;
    const int tstart = dir ? (c * CL + CL - 1 + warm) : (c * CL - warm);

    const float* table = dir ? tableB : tableF;
    const float* Whh   = dir ? WhhB : WhhF;
    float* emOut       = dir ? emB : emF;

    __shared__ __align__(16) unsigned short h_lds[2][16][264];  // [buf][b][col]

    const int colg = jb * 128 + wv * 16 + lo;     // this lane's h-col (0..255)
    const int bb0 = g * GB;
    const int pbase = (jb ^ 1) * 2048;            // partner half, u32 words
    const int pcol  = (jb ^ 1) * 128 + (tid >> 2);
    const int pb0   = (tid & 3) * 4;
    unsigned* slab0 = hws + (size_t)(gi2 * 2) * 4096;   // + parity*4096

    // ---- preload Whh B-fragments: B[k][col] = Whh[q*HH+colg][k] ----
    short8 wfrag[4][8];
#pragma unroll
    for (int q = 0; q < 4; ++q) {
        const float* wrow = Whh + (size_t)(q * HH + colg) * HH;
#pragma unroll
        for (int kb = 0; kb < 8; ++kb) {
            const float4* p4 = (const float4*)(wrow + kb * 32 + hi * 8);
            float4 a = p4[0], b = p4[1];
            short8 f;
            f[0] = (short)f2b(a.x); f[1] = (short)f2b(a.y);
            f[2] = (short)f2b(a.z); f[3] = (short)f2b(a.w);
            f[4] = (short)f2b(b.x); f[5] = (short)f2b(b.y);
            f[6] = (short)f2b(b.z); f[7] = (short)f2b(b.w);
            wfrag[q][kb] = f;
        }
    }
    // ---- em B-fragments (fcW), used by block jb==0 wave 0 only ----
    short8 efrag[8];
    if (jb == 0 && wv == 0) {
#pragma unroll
        for (int kb = 0; kb < 8; ++kb) {
            short8 f;
            if (lo < KK) {
                const float4* p4 = (const float4*)(fcW + lo * (2 * HH) + dir * HH + kb * 32 + hi * 8);
                float4 a = p4[0], b = p4[1];
                f[0] = (short)f2b(a.x); f[1] = (short)f2b(a.y);
                f[2] = (short)f2b(a.z); f[3] = (short)f2b(a.w);
                f[4] = (short)f2b(b.x); f[5] = (short)f2b(b.y);
                f[6] = (short)f2b(b.z); f[7] = (short)f2b(b.w);
            } else {
                for (int j = 0; j < 8; ++j) f[j] = 0;
            }
            efrag[kb] = f;
        }
    }

    float cst[4] = {0.f, 0.f, 0.f, 0.f};

    for (int s = 0; s <= S; ++s) {
        // ---- (1) table gather first: hides L2 latency under the poll ----
        float tv[16];
        if (s < S) {
            const int t = dir ? (tstart - s) : (tstart + s);
            int cid[4];
#pragma unroll
            for (int r = 0; r < 4; ++r) cid[r] = cidsT[t * BB + bb0 + hi * 4 + r];
#pragma unroll
            for (int q = 0; q < 4; ++q)
#pragma unroll
                for (int r = 0; r < 4; ++r)
                    tv[q * 4 + r] = table[(size_t)cid[r] * 1024 + q * HH + colg];
        }

        // ---- (2) poll partner half of h_{s-1}: 4-deep pipelined ring ----
        if (s > 0) {
            const unsigned* psrc = slab0 + ((s + 1) & 1) * 4096 + pbase + tid * 4;
            const unsigned want = ((unsigned)s) << 16;
            uint4v r0, r1, r2, r3, wres;
            asm volatile("global_load_dwordx4 %0, %1, off sc0 sc1" : "=v"(r0) : "v"(psrc) : "memory");
            asm volatile("global_load_dwordx4 %0, %1, off sc0 sc1" : "=v"(r1) : "v"(psrc) : "memory");
            asm volatile("global_load_dwordx4 %0, %1, off sc0 sc1" : "=v"(r2) : "v"(psrc) : "memory");
            asm volatile("global_load_dwordx4 %0, %1, off sc0 sc1" : "=v"(r3) : "v"(psrc) : "memory");
#define CHK(RR) (((RR[0] & 0xffff0000u) == want) & ((RR[1] & 0xffff0000u) == want) & \
                 ((RR[2] & 0xffff0000u) == want) & ((RR[3] & 0xffff0000u) == want))
            for (;;) {
                asm volatile("s_waitcnt vmcnt(3)" ::: "memory");
                __builtin_amdgcn_sched_barrier(0);
                if (CHK(r0)) { wres = r0; break; }
                asm volatile("global_load_dwordx4 %0, %1, off sc0 sc1" : "=v"(r0) : "v"(psrc) : "memory");
                asm volatile("s_waitcnt vmcnt(3)" ::: "memory");
                __builtin_amdgcn_sched_barrier(0);
                if (CHK(r1)) { wres = r1; break; }
                asm volatile("global_load_dwordx4 %0, %1, off sc0 sc1" : "=v"(r1) : "v"(psrc) : "memory");
                asm volatile("s_waitcnt vmcnt(3)" ::: "memory");
                __builtin_amdgcn_sched_barrier(0);
                if (CHK(r2)) { wres = r2; break; }
                asm volatile("global_load_dwordx4 %0, %1, off sc0 sc1" : "=v"(r2) : "v"(psrc) : "memory");
                asm volatile("s_waitcnt vmcnt(3)" ::: "memory");
                __builtin_amdgcn_sched_barrier(0);
                if (CHK(r3)) { wres = r3; break; }
                asm volatile("global_load_dwordx4 %0, %1, off sc0 sc1" : "=v"(r3) : "v"(psrc) : "memory");
            }
#undef CHK
            asm volatile("s_waitcnt vmcnt(0)" ::: "memory");
            __builtin_amdgcn_sched_barrier(0);
            unsigned short (*hl)[264] = h_lds[s & 1];
            hl[pb0 + 0][pcol] = (unsigned short)wres[0];
            hl[pb0 + 1][pcol] = (unsigned short)wres[1];
            hl[pb0 + 2][pcol] = (unsigned short)wres[2];
            hl[pb0 + 3][pcol] = (unsigned short)wres[3];
        }
        __syncthreads();

        // ---- (3) gates MFMA + nonlinearity + tagged h store + own-half LDS write ----
        if (s < S) {
            floatx4 acc[4];
#pragma unroll
            for (int q = 0; q < 4; ++q) {
                acc[q][0] = tv[q * 4 + 0]; acc[q][1] = tv[q * 4 + 1];
                acc[q][2] = tv[q * 4 + 2]; acc[q][3] = tv[q * 4 + 3];
            }
            if (s > 0) {
                const unsigned short (*hl)[264] = h_lds[s & 1];
#pragma unroll
                for (int kb = 0; kb < 8; ++kb) {
                    short8 a = *(const short8*)&hl[lo][kb * 32 + hi * 8];
#pragma unroll
                    for (int q = 0; q < 4; ++q)
                        acc[q] = __builtin_amdgcn_mfma_f32_16x16x32_bf16(a, wfrag[q][kb], acc[q], 0, 0, 0);
                }
            }
            unsigned hb[4];
#pragma unroll
            for (int r = 0; r < 4; ++r) {
                float iv = acc[0][r], fv = acc[1][r], gv = acc[2][r], ov = acc[3][r];
                float cn = fsig(fv) * cst[r] + fsig(iv) * ftanh(gv);
                cst[r] = cn;
                hb[r] = (unsigned)f2b(fsig(ov) * ftanh(cn));
            }
            const unsigned tagw = ((unsigned)(s + 1)) << 16;
            uint4v pv;
            pv[0] = tagw | hb[0]; pv[1] = tagw | hb[1];
            pv[2] = tagw | hb[2]; pv[3] = tagw | hb[3];
            unsigned* dst = slab0 + (s & 1) * 4096 + colg * 16 + hi * 4;
            asm volatile("global_store_dwordx4 %0, %1, off sc0 sc1"
                         :: "v"(dst), "v"(pv) : "memory");
            // own half straight into next step's LDS buffer
            unsigned short (*hw)[264] = h_lds[(s + 1) & 1];
            hw[hi * 4 + 0][colg] = (unsigned short)hb[0];
            hw[hi * 4 + 1][colg] = (unsigned short)hb[1];
            hw[hi * 4 + 2][colg] = (unsigned short)hb[2];
            hw[hi * 4 + 3][colg] = (unsigned short)hb[3];
        }

        // ---- (4) em for h_{s-1} (lagged), only for this chunk's real t-range ----
        if (s > 0 && (s - 1) >= warm && jb == 0 && wv == 0) {
            const unsigned short (*hl)[264] = h_lds[s & 1];
            floatx4 eacc = {0.f, 0.f, 0.f, 0.f};
#pragma unroll
            for (int kb = 0; kb < 8; ++kb) {
                short8 a = *(const short8*)&hl[lo][kb * 32 + hi * 8];
                eacc = __builtin_amdgcn_mfma_f32_16x16x32_bf16(a, efrag[kb], eacc, 0, 0, 0);
            }
            if (lo < KK) {
                const int te = dir ? (tstart - (s - 1)) : (tstart + (s - 1));
                float* eo = emOut + (size_t)(te * BB + bb0) * KK + lo;
#pragma unroll
                for (int r = 0; r < 4; ++r)
                    eo[(hi * 4 + r) * KK] = eacc[r];
            }
        }
    }
}

// ---------------- CRF partition (den): 16-lane group per batch row, em prefetch ----------------
__global__ void crf_den(const float* __restrict__ emF, const float* __restrict__ emB,
                        const float* __restrict__ fcb, const float* __restrict__ start_t,
                        const float* __restrict__ end_t, const float* __restrict__ trans,
                        float* __restrict__ den) {
    const int tid = threadIdx.x;
    const int j = tid & 15;
    const int grp = tid >> 4;               // 0..7
    const int b = blockIdx.x * 8 + grp;
    const bool valid = j < KK;

    __shared__ float expT[15][16];
    for (int idx = tid; idx < 240; idx += 128) {
        int i = idx >> 4, jj = idx & 15;
        expT[i][jj] = (jj < KK) ? __expf(trans[i * KK + jj]) : 0.f;
    }
    __syncthreads();

    float fcbj = valid ? fcb[j] : 0.f;
    float alpha = -1e30f;
    if (valid) alpha = start_t[j] + emF[b * KK + j] + emB[b * KK + j] + fcbj;

    float emv_nxt = 0.f;
    if (valid) emv_nxt = emF[(1 * BB + b) * KK + j] + emB[(1 * BB + b) * KK + j];

    for (int t = 1; t < TT; ++t) {
        float emv = emv_nxt;
        if (valid && t + 1 < TT)
            emv_nxt = emF[((t + 1) * BB + b) * KK + j] + emB[((t + 1) * BB + b) * KK + j];
        float m = alpha;
#pragma unroll
        for (int off = 8; off; off >>= 1)
            m = fmaxf(m, __shfl_xor(m, off, 16));
        float e = __expf(alpha - m);
        float S = 0.f;
#pragma unroll
        for (int i = 0; i < KK; ++i)
            S += __shfl(e, i, 16) * expT[i][j];
        float na = m + __logf(S) + emv + fcbj;
        alpha = valid ? na : -1e30f;
    }
    float v = valid ? (alpha + end_t[j]) : -1e30f;
    float m = v;
#pragma unroll
    for (int off = 8; off; off >>= 1) m = fmaxf(m, __shfl_xor(m, off, 16));
    float e = __expf(v - m);
#pragma unroll
    for (int off = 8; off; off >>= 1) e += __shfl_xor(e, off, 16);
    if (j == 0) den[b] = m + __logf(e);
}

// ---------------- CRF numerator partials over t-chunks ----------------
__global__ void crf_num_part(const float* __restrict__ emF, const float* __restrict__ emB,
                             const float* __restrict__ fcb, const float* __restrict__ start_t,
                             const float* __restrict__ trans, const int* __restrict__ labelsT,
                             float* __restrict__ part) {
    const int b = threadIdx.x;
    const int q = blockIdx.x;
    const int t0 = q * 64;
    float p = 0.f;
    int lp = (t0 > 0) ? labelsT[(t0 - 1) * BB + b] : 0;
    for (int t = t0; t < t0 + 64; ++t) {
        int l = labelsT[t * BB + b];
        float em = emF[(t * BB + b) * KK + l] + emB[(t * BB + b) * KK + l] + fcb[l];
        if (t == 0) p += start_t[l] + em;
        else        p += trans[lp * KK + l] + em;
        lp = l;
    }
    part[q * BB + b] = p;
}

// ---------------- finalize ----------------
__global__ void finalize(const float* __restrict__ part, const float* __restrict__ den,
                         const float* __restrict__ end_t, const int* __restrict__ labelsT,
                         float* __restrict__ out) {
    const int b = threadIdx.x;
    float num = 0.f;
#pragma unroll
    for (int q = 0; q < 8; ++q) num += part[q * BB + b];
    num += end_t[labelsT[(TT - 1) * BB + b]];
    float v = num - den[b];
    __shared__ float red[256];
    red[b] = v;
    __syncthreads();
    for (int st = 128; st; st >>= 1) {
        if (b < st) red[b] += red[b + st];
        __syncthreads();
    }
    if (b == 0) out[0] = -(red[0] / (float)BB);
}

extern "C" void kernel_launch(void* const* d_in, const int* in_sizes, int n_in,
                              void* d_out, int out_size, void* d_ws, size_t ws_size,
                              hipStream_t stream) {
    const int* char_ids   = (const int*)d_in[0];
    const int* labels     = (const int*)d_in[1];
    const float* embed    = (const float*)d_in[3];
    const float* WihF     = (const float*)d_in[4];
    const float* WhhF     = (const float*)d_in[5];
    const float* bF       = (const float*)d_in[6];
    const float* WihB     = (const float*)d_in[7];
    const float* WhhB     = (const float*)d_in[8];
    const float* bB       = (const float*)d_in[9];
    const float* fcW      = (const float*)d_in[10];
    const float* fcb      = (const float*)d_in[11];
    const float* start_t  = (const float*)d_in[12];
    const float* end_t    = (const float*)d_in[13];
    const float* trans    = (const float*)d_in[14];

    char* w = (char*)d_ws;
    float* tableF = (float*)w;          w += 128 * 1024 * 4;
    float* tableB = (float*)w;          w += 128 * 1024 * 4;
    int* cidsT    = (int*)w;            w += 512 * 256 * 4;
    int* labelsT  = (int*)w;            w += 512 * 256 * 4;
    unsigned* hws = (unsigned*)w;       w += 128 * 2 * 4096 * 4;      // 4 MiB
    float* emF    = (float*)w;          w += 512 * 256 * 15 * 4;
    float* emB    = (float*)w;          w += 512 * 256 * 15 * 4;
    float* den    = (float*)w;          w += 256 * 4;
    float* part   = (float*)w;          w += 8 * 256 * 4;

    hipMemsetAsync(hws, 0, 128 * 2 * 4096 * 4, stream);
    prep_fused<<<2048, 256, 0, stream>>>(char_ids, labels, cidsT, labelsT,
                                         embed, WihF, bF, WihB, bB, tableF, tableB);

    void* args[] = { (void*)&tableF, (void*)&tableB, (void*)&WhhF, (void*)&WhhB,
                     (void*)&fcW, (void*)&cidsT, (void*)&hws, (void*)&emF, (void*)&emB };
    hipLaunchCooperativeKernel((void*)bilstm, dim3(256), dim3(512), args, 0, stream);

    crf_den<<<32, 128, 0, stream>>>(emF, emB, fcb, start_t, end_t, trans, den);
    crf_num_part<<<8, 256, 0, stream>>>(emF, emB, fcb, start_t, trans, labelsT, part);
    finalize<<<1, 256, 0, stream>>>(part, den, end_t, labelsT, (float*)d_out);
}